// Round 15
// baseline (189.838 us; speedup 1.0000x reference)
//
#include <hip/hip_runtime.h>

#define SEQ 4096
#define DM 1024
#define NH 16
#define HD 64

typedef __attribute__((ext_vector_type(8))) short short8;
typedef __attribute__((ext_vector_type(4))) short short4v;
typedef __attribute__((ext_vector_type(2))) short short2v;
typedef __attribute__((ext_vector_type(4))) float float4v;
typedef __attribute__((ext_vector_type(4))) int int4v;

__device__ __forceinline__ short f2bf(float f) {
    union { float f; unsigned u; } v; v.f = f;
    unsigned u = v.u;
    return (short)((u + 0x7fffu + ((u >> 16) & 1u)) >> 16);
}
// pack two fp32 -> dword of two bf16 via HW cvt_pk (1 VALU; no builtin on gfx950)
__device__ __forceinline__ int cvtpk(float lo, float hi) {
    int r;
    asm("v_cvt_pk_bf16_f32 %0, %1, %2" : "=v"(r) : "v"(lo), "v"(hi));
    return r;
}

__device__ __forceinline__ void gload_lds16(const void* g, void* l) {
    __builtin_amdgcn_global_load_lds(
        (const __attribute__((address_space(1))) void*)g,
        (__attribute__((address_space(3))) void*)l, 16, 0, 0);
}

// ---- fused prep: cast x (fp32->bf16) + transpose_cast Wqkv + transpose_cast Wout ----
// 3 launches -> 1. Flat 8192-block grid:
//   [0,4096): cast_x float4 blocks; [4096,7168): Wqkv 32x32 transpose tiles;
//   [7168,8192): Wout tiles. 256 threads flat; transpose remaps to (32,8).
__global__ __launch_bounds__(256) void prep(const float* __restrict__ x,
                                            const float* __restrict__ Wqkv,
                                            const float* __restrict__ Wout,
                                            short* __restrict__ xb,
                                            short* __restrict__ wqkvT,
                                            short* __restrict__ woutT) {
    __shared__ float tile[32][33];
    int bid = blockIdx.x;
    int tid = threadIdx.x;
    if (bid < 4096) {
        int i = bid * 256 + tid;               // SEQ*DM/4 float4 elems
        float4v v = ((const float4v*)x)[i];
        short4v o;
        o[0] = f2bf(v[0]); o[1] = f2bf(v[1]); o[2] = f2bf(v[2]); o[3] = f2bf(v[3]);
        ((short4v*)xb)[i] = o;
        return;
    }
    const float* in;
    short* out;
    int W, bxi, byi;
    float scale;
    int scaled_rows;
    if (bid < 4096 + 3072) {                   // Wqkv: [1024][3072] -> [3072][1024]
        int b = bid - 4096;
        in = Wqkv; out = wqkvT; W = 3 * DM;
        bxi = b % 96; byi = b / 96;
        scale = 0.18033688011112042f;          // (1/sqrt(64)) * log2(e)
        scaled_rows = DM;
    } else {                                   // Wout: [1024][1024] -> [1024][1024]
        int b = bid - 7168;
        in = Wout; out = woutT; W = DM;
        bxi = b % 32; byi = b / 32;
        scale = 1.0f;
        scaled_rows = 0;
    }
    int bx = bxi * 32, by = byi * 32;
    int tx = tid & 31, ty = tid >> 5;          // 32 x 8
#pragma unroll
    for (int i = 0; i < 32; i += 8)
        tile[ty + i][tx] = in[(by + ty + i) * W + bx + tx];
    __syncthreads();
#pragma unroll
    for (int i = 0; i < 32; i += 8) {
        int orow = bx + ty + i;
        float sc = (orow < scaled_rows) ? scale : 1.0f;
        out[orow * DM + by + tx] = f2bf(tile[tx][ty + i] * sc);
    }
}

// ------- V transpose: qkv bf16 [l][2048+h*64+d] -> vt [h][d][swz(l)] -------
// k-swizzle within each 32-col block so the attn PV B-fragment (k-permuted MFMA)
// reads plain short8 at quad*8: swz(s) = (s&~31)|((s&12)<<1)|((s&16)>>2)|(s&3).
__global__ void transpose_v(const short* __restrict__ qkv, short* __restrict__ vt) {
    __shared__ short tile[64][66];
    int h = blockIdx.z;
    int l0 = blockIdx.x * 64;
    int tx = threadIdx.x, ty = threadIdx.y;   // 32 x 8
#pragma unroll
    for (int i = 0; i < 8; i++) {
        int r = ty + i * 8;
        short2v v = *(const short2v*)&qkv[(l0 + r) * (3 * DM) + 2 * DM + h * HD + 2 * tx];
        tile[r][2 * tx] = v[0];
        tile[r][2 * tx + 1] = v[1];
    }
    __syncthreads();
#pragma unroll
    for (int i = 0; i < 8; i++) {
        int d = ty + i * 8;
        short2v v;
        v[0] = tile[2 * tx][d];
        v[1] = tile[2 * tx + 1][d];
        int s = l0 + 2 * tx;   // even -> swz keeps the pair contiguous
        int soff = (s & ~31) | ((s & 12) << 1) | ((s & 16) >> 2) | (s & 3);
        *(short2v*)&vt[(h * HD + d) * SEQ + soff] = v;
    }
}

// ------------- GEMM: A[M,K] bf16 x BT[N,K] bf16 -> C[M,N], 128x128 tile -------------
// R17-exact (session best): BK=64 + both-sides XOR swizzle, natural block order.
template <typename OutT>
__global__ __launch_bounds__(256) void gemm_bt(const short* __restrict__ A,
                                               const short* __restrict__ BT,
                                               OutT* __restrict__ C,
                                               int M, int N, int K) {
    __shared__ short As[128 * 64];   // 16 KB
    __shared__ short Bs[128 * 64];   // 16 KB
    int tid  = threadIdx.x;
    int m0   = blockIdx.y * 128;
    int n0   = blockIdx.x * 128;
    int w    = tid >> 6, lane = tid & 63;
    int wm   = w >> 1,  wn   = w & 1;
    int quad = lane >> 4, l15 = lane & 15;
    int lrow = lane >> 3;            // 0..7 row within 8-row DMA stripe
    int cg   = (lane & 7) ^ lrow;    // pre-swizzled source chunk
    int xr   = (l15 & 7) * 8;        // read-side XOR, in shorts

    float4v acc[4][4];
#pragma unroll
    for (int mi = 0; mi < 4; mi++)
#pragma unroll
        for (int ni = 0; ni < 4; ni++)
            acc[mi][ni] = {0.f, 0.f, 0.f, 0.f};

    for (int k0 = 0; k0 < K; k0 += 64) {
        __syncthreads();
#pragma unroll
        for (int t = 0; t < 4; t++) {
            int c = w * 4 + t;           // 16 chunks of 8 rows
            int r = c * 8 + lrow;
            gload_lds16(&A[(m0 + r) * K + k0 + cg * 8], &As[c * 8 * 64]);
            gload_lds16(&BT[(n0 + r) * K + k0 + cg * 8], &Bs[c * 8 * 64]);
        }
        __syncthreads();
        short8 a[4][2], b[4][2];
#pragma unroll
        for (int mi = 0; mi < 4; mi++)
#pragma unroll
            for (int kk = 0; kk < 2; kk++)
                a[mi][kk] = *(const short8*)&As[(wm * 64 + mi * 16 + l15) * 64 + (((kk * 4 + quad) * 8) ^ xr)];
#pragma unroll
        for (int ni = 0; ni < 4; ni++)
#pragma unroll
            for (int kk = 0; kk < 2; kk++)
                b[ni][kk] = *(const short8*)&Bs[(wn * 64 + ni * 16 + l15) * 64 + (((kk * 4 + quad) * 8) ^ xr)];
#pragma unroll
        for (int kk = 0; kk < 2; kk++)
#pragma unroll
            for (int mi = 0; mi < 4; mi++)
#pragma unroll
                for (int ni = 0; ni < 4; ni++)
                    acc[mi][ni] = __builtin_amdgcn_mfma_f32_16x16x32_bf16(a[mi][kk], b[ni][kk], acc[mi][ni], 0, 0, 0);
    }

#pragma unroll
    for (int mi = 0; mi < 4; mi++)
#pragma unroll
        for (int ni = 0; ni < 4; ni++)
#pragma unroll
            for (int r = 0; r < 4; r++) {
                int row = m0 + wm * 64 + mi * 16 + quad * 4 + r;
                int col = n0 + wn * 64 + ni * 16 + l15;
                float v = acc[mi][ni][r];
                if constexpr (sizeof(OutT) == 2) C[row * N + col] = (OutT)f2bf(v);
                else                             C[row * N + col] = (OutT)v;
            }
}

// ------------- GEMM 64x128 tile (small-N GEMM2; BK=64 + both-sides XOR swizzle) -------------
__global__ __launch_bounds__(256) void gemm_bt64(const short* __restrict__ A,
                                                 const short* __restrict__ BT,
                                                 float* __restrict__ C,
                                                 int M, int N, int K) {
    __shared__ short As[64 * 64];    // 8 KB
    __shared__ short Bs[128 * 64];   // 16 KB
    int tid  = threadIdx.x;
    int m0   = blockIdx.y * 64;
    int n0   = blockIdx.x * 128;
    int w    = tid >> 6, lane = tid & 63;
    int wm   = w >> 1,  wn   = w & 1;
    int quad = lane >> 4, l15 = lane & 15;
    int lrow = lane >> 3;
    int cg   = (lane & 7) ^ lrow;
    int xr   = (l15 & 7) * 8;

    float4v acc[2][4];
#pragma unroll
    for (int mi = 0; mi < 2; mi++)
#pragma unroll
        for (int ni = 0; ni < 4; ni++)
            acc[mi][ni] = {0.f, 0.f, 0.f, 0.f};

    for (int k0 = 0; k0 < K; k0 += 64) {
        __syncthreads();
#pragma unroll
        for (int t = 0; t < 2; t++) {
            int c = w * 2 + t;           // 8 chunks of 8 rows (A: 64 rows)
            int r = c * 8 + lrow;
            gload_lds16(&A[(m0 + r) * K + k0 + cg * 8], &As[c * 8 * 64]);
        }
#pragma unroll
        for (int t = 0; t < 4; t++) {
            int c = w * 4 + t;           // 16 chunks of 8 rows (B: 128 rows)
            int r = c * 8 + lrow;
            gload_lds16(&BT[(n0 + r) * K + k0 + cg * 8], &Bs[c * 8 * 64]);
        }
        __syncthreads();
        short8 a[2][2], b[4][2];
#pragma unroll
        for (int mi = 0; mi < 2; mi++)
#pragma unroll
            for (int kk = 0; kk < 2; kk++)
                a[mi][kk] = *(const short8*)&As[(wm * 32 + mi * 16 + l15) * 64 + (((kk * 4 + quad) * 8) ^ xr)];
#pragma unroll
        for (int ni = 0; ni < 4; ni++)
#pragma unroll
            for (int kk = 0; kk < 2; kk++)
                b[ni][kk] = *(const short8*)&Bs[(wn * 64 + ni * 16 + l15) * 64 + (((kk * 4 + quad) * 8) ^ xr)];
#pragma unroll
        for (int kk = 0; kk < 2; kk++)
#pragma unroll
            for (int mi = 0; mi < 2; mi++)
#pragma unroll
                for (int ni = 0; ni < 4; ni++)
                    acc[mi][ni] = __builtin_amdgcn_mfma_f32_16x16x32_bf16(a[mi][kk], b[ni][kk], acc[mi][ni], 0, 0, 0);
    }

#pragma unroll
    for (int mi = 0; mi < 2; mi++)
#pragma unroll
        for (int ni = 0; ni < 4; ni++)
#pragma unroll
            for (int r = 0; r < 4; r++) {
                int row = m0 + wm * 32 + mi * 16 + quad * 4 + r;
                int col = n0 + wn * 64 + ni * 16 + l15;
                C[row * N + col] = acc[mi][ni][r];
            }
}

// ------------- flash attention, causal, bf16 MFMA, DMA-staged K/V -------------
// R21 (two tiles per barrier pair, WIN 59->50.5 us) + R22: per-wave fully-masked
// tile skip. Waves 0,1 of each q-tile's low half see their final s-tile fully
// masked (s0 > qw+63 -> P == 0): skip kc/vc reads + QK + exp + pack for them,
// still fire the deferred PV(prev), then zero pa_p so the carried final-PV is a
// no-op (identical result to computing the masked tile). Wave-uniform branch;
// staging and barriers unchanged (cooperative/block-wide).
__global__ __launch_bounds__(256, 2) void attn_kernel(const short* __restrict__ qkv,
                                                      const short* __restrict__ vtp,
                                                      float* __restrict__ Of0,
                                                      float* __restrict__ Of1,
                                                      float* __restrict__ Of2,
                                                      float* __restrict__ Lf0,
                                                      float* __restrict__ Lf1,
                                                      float* __restrict__ Lf2) {
    __shared__ short Ks[4][64 * 64];    // linear, DMA-written (8 KB each; 64 KB total K+V)
    __shared__ short Vs[4][64 * 64];
    int gid = blockIdx.x;            // 0..767
    int rr = gid & 7, qq = gid >> 3; // qq 0..95; gid%8 pins XCD = h%8 (2 heads/XCD)
    int hb = qq / 48;
    int rem = qq - hb * 48;          // 0..47
    int h = rr + 8 * hb;
    int b = rem & 15;                // pair index: q-tiles (b, 31-b)
    int j = rem >> 4;                // job 0..2 -> partial buffer j
    float* __restrict__ Of = (j == 0) ? Of0 : (j == 1) ? Of1 : Of2;
    float* __restrict__ Lf = (j == 0) ? Lf0 : (j == 1) ? Lf1 : Lf2;
    int B0 = 2 * b + 2;              // concat boundary between the pair's q-tiles

    int tid = threadIdx.x;
    int w = tid >> 6, lane = tid & 63;
    int quad = lane >> 4, l15 = lane & 15;
    int rowb = w * 16;               // wave's 16 staging rows
    int lrow = lane >> 3;            // 0..7: row within the 8-row DMA stripe
    int cg   = (lane & 7) ^ lrow;    // pre-swizzled source chunk (XOR both-sides)
    int xr   = (l15 & 7) * 8;        // read-side XOR, in shorts

    const short* Kg = qkv + DM + h * HD;     // + s*3072 + chunk*8
    const short* Vg = vtp + (h * HD) * SEQ;  // + d*4096 + s + chunk*8

    short8 onesv;                    // bf16 1.0 x8 (B-operand for l-accumulation MFMA)
#pragma unroll
    for (int i = 0; i < 8; i++) onesv[i] = (short)0x3F80;

#pragma unroll 1
    for (int sg = 0; sg < 2; sg++) {
        int t, st0, stN;
        if (sg == 0) {               // segment in q-tile b: concat tiles [22j,22j+22) ∩ [0,B0)
            t = b;
            st0 = 22 * j;
            stN = (22 * j + 22 < B0) ? 22 * j + 22 : B0;
        } else {                     // segment in q-tile 31-b: concat ∩ [B0,66), rebased
            t = 31 - b;
            int a0 = 22 * j - B0;
            st0 = (a0 > 0) ? a0 : 0;
            stN = 22 * j + 22 - B0;
        }
        if (st0 >= stN) continue;    // block-uniform

        int q0 = t * 128;
        int qw = q0 + w * 32;

        // Q fragments (B-operand of the S^T MFMA); Q pre-scaled by 0.125*log2e
        short8 aq[2][2];
#pragma unroll
        for (int mi = 0; mi < 2; mi++)
#pragma unroll
            for (int kk = 0; kk < 2; kk++)
                aq[mi][kk] = *(const short8*)&qkv[(qw + mi * 16 + l15) * (3 * DM) + h * HD + kk * 32 + quad * 8];

        float4v lacc[2];
        float4v o[2][4];
#pragma unroll
        for (int mi = 0; mi < 2; mi++) {
            lacc[mi] = {0.f, 0.f, 0.f, 0.f};
#pragma unroll
            for (int dt = 0; dt < 4; dt++)
                o[mi][dt] = {0.f, 0.f, 0.f, 0.f};
        }

        // DMA-stage one 64-s K/V tile into LDS slot (4 gload_lds per wave)
        auto stage = [&](int slot, int tt_) {
            int s0_ = tt_ * 64;
#pragma unroll
            for (int i = 0; i < 2; i++) {
                int r = rowb + i * 8;
                gload_lds16(&Kg[(s0_ + r + lrow) * (3 * DM) + cg * 8], &Ks[slot][r * 64]);
                gload_lds16(&Vg[(r + lrow) * SEQ + s0_ + cg * 8],      &Vs[slot][r * 64]);
            }
        };

        short8 pa_p[2][2];   // P(prev tile) bf16 fragments, loop-carried
        short8 vc_p[8];      // V(prev tile) fragments, loop-carried (refilled in place)

        // per-tile body: kc reads -> PV(prev) under read shadow -> vc_p refill ->
        // QK -> mask/exp -> pack into pa_p.  Fully-masked tiles (s0 > qw+63, wave-
        // uniform) fire only PV(prev) and zero pa_p (equivalent to masked compute).
        auto procTile = [&](int slot, int tt, bool doPV) {
            const short* Kb = &Ks[slot][0];
            const short* Vb = &Vs[slot][0];
            int s0 = tt * 64;

            if (s0 > qw + 63) {      // fully masked for this wave: P == 0
                if (doPV) {
                    __builtin_amdgcn_s_setprio(1);
#pragma unroll
                    for (int mi = 0; mi < 2; mi++)
#pragma unroll
                        for (int pr = 0; pr < 2; pr++)
                            lacc[mi] = __builtin_amdgcn_mfma_f32_16x16x32_bf16(pa_p[mi][pr], onesv, lacc[mi], 0, 0, 0);
#pragma unroll
                    for (int mi = 0; mi < 2; mi++)
#pragma unroll
                        for (int dt = 0; dt < 4; dt++)
#pragma unroll
                            for (int pr = 0; pr < 2; pr++)
                                o[mi][dt] = __builtin_amdgcn_mfma_f32_16x16x32_bf16(pa_p[mi][pr], vc_p[dt * 2 + pr], o[mi][dt], 0, 0, 0);
                    __builtin_amdgcn_s_setprio(0);
                }
                int4v z = {0, 0, 0, 0};
#pragma unroll
                for (int mi = 0; mi < 2; mi++)
#pragma unroll
                    for (int pr = 0; pr < 2; pr++)
                        pa_p[mi][pr] = *(short8*)&z;   // carried final-PV becomes no-op
                return;
            }

            short8 kc[8];
#pragma unroll
            for (int ni = 0; ni < 4; ni++)
#pragma unroll
                for (int kk = 0; kk < 2; kk++)
                    kc[ni * 2 + kk] = *(const short8*)&Kb[(ni * 16 + l15) * 64 + (((kk * 4 + quad) * 8) ^ xr)];

            if (doPV) {
                __builtin_amdgcn_s_setprio(1);
#pragma unroll
                for (int mi = 0; mi < 2; mi++)
#pragma unroll
                    for (int pr = 0; pr < 2; pr++)
                        lacc[mi] = __builtin_amdgcn_mfma_f32_16x16x32_bf16(pa_p[mi][pr], onesv, lacc[mi], 0, 0, 0);
#pragma unroll
                for (int mi = 0; mi < 2; mi++)
#pragma unroll
                    for (int dt = 0; dt < 4; dt++)
#pragma unroll
                        for (int pr = 0; pr < 2; pr++)
                            o[mi][dt] = __builtin_amdgcn_mfma_f32_16x16x32_bf16(pa_p[mi][pr], vc_p[dt * 2 + pr], o[mi][dt], 0, 0, 0);
                __builtin_amdgcn_s_setprio(0);
            }

#pragma unroll
            for (int dt = 0; dt < 4; dt++)
#pragma unroll
                for (int pr = 0; pr < 2; pr++)
                    vc_p[dt * 2 + pr] = *(const short8*)&Vb[(dt * 16 + l15) * 64 + (((pr * 4 + quad) * 8) ^ xr)];

            float4v s[2][4];
            __builtin_amdgcn_s_setprio(1);
#pragma unroll
            for (int mi = 0; mi < 2; mi++)
#pragma unroll
                for (int ni = 0; ni < 4; ni++) {
                    float4v a = {0.f, 0.f, 0.f, 0.f};
#pragma unroll
                    for (int kk = 0; kk < 2; kk++)
                        a = __builtin_amdgcn_mfma_f32_16x16x32_bf16(kc[ni * 2 + kk], aq[mi][kk], a, 0, 0, 0);
                    s[mi][ni] = a;
                }
            __builtin_amdgcn_s_setprio(0);

            bool diag = (s0 + 63 > qw);
            if (diag) {
#pragma unroll
                for (int mi = 0; mi < 2; mi++) {
                    int qrow = qw + mi * 16 + l15;
#pragma unroll
                    for (int ni = 0; ni < 4; ni++)
#pragma unroll
                        for (int r = 0; r < 4; r++) {
                            float p = __builtin_amdgcn_exp2f(s[mi][ni][r]);
                            int scol = s0 + ni * 16 + quad * 4 + r;
                            s[mi][ni][r] = (scol <= qrow) ? p : 0.f;
                        }
                }
            } else {
#pragma unroll
                for (int mi = 0; mi < 2; mi++)
#pragma unroll
                    for (int ni = 0; ni < 4; ni++)
#pragma unroll
                        for (int r = 0; r < 4; r++)
                            s[mi][ni][r] = __builtin_amdgcn_exp2f(s[mi][ni][r]);
            }
#pragma unroll
            for (int mi = 0; mi < 2; mi++)
#pragma unroll
                for (int pr = 0; pr < 2; pr++) {
                    int4v wpk;
                    wpk[0] = cvtpk(s[mi][2 * pr][0], s[mi][2 * pr][1]);
                    wpk[1] = cvtpk(s[mi][2 * pr][2], s[mi][2 * pr][3]);
                    wpk[2] = cvtpk(s[mi][2 * pr + 1][0], s[mi][2 * pr + 1][1]);
                    wpk[3] = cvtpk(s[mi][2 * pr + 1][2], s[mi][2 * pr + 1][3]);
                    pa_p[mi][pr] = *(short8*)&wpk;
                }
        };

        // prologue: stage first (up to) 2 tiles into slots 0,1
        stage(0, st0);
        if (st0 + 1 < stN) stage(1, st0 + 1);
        asm volatile("s_waitcnt vmcnt(0)" ::: "memory");
        __builtin_amdgcn_s_barrier();
        __builtin_amdgcn_sched_barrier(0);

        int L = stN - st0;
        int tt = st0, si = 0;
        bool first = true;

        if (L & 1) {                 // single-tile lead-in phase
            if (tt + 2 < stN) stage(2, tt + 2);
            procTile(0, tt, false);
            asm volatile("s_waitcnt lgkmcnt(0)" ::: "memory");
            asm volatile("s_waitcnt vmcnt(0)" ::: "memory");
            __builtin_amdgcn_s_barrier();
            __builtin_amdgcn_sched_barrier(0);
            tt += 1; si = 1; first = false;
        }

        for (; tt < stN; tt += 2) {  // two tiles per barrier pair
            int sA = si, sB = (si + 1) & 3, sC = (si + 2) & 3, sD = (si + 3) & 3;
            if (tt + 2 < stN) stage(sC, tt + 2);
            if (tt + 3 < stN) stage(sD, tt + 3);

            procTile(sA, tt, !first);
            procTile(sB, tt + 1, true);
            first = false;

            asm volatile("s_waitcnt lgkmcnt(0)" ::: "memory");
            asm volatile("s_waitcnt vmcnt(0)" ::: "memory");
            __builtin_amdgcn_s_barrier();
            __builtin_amdgcn_sched_barrier(0);
            si = sC;
        }

        // final deferred PV + l of tile stN-1 (carried in pa_p / vc_p; pa_p == 0
        // if that tile was fully masked for this wave)
        __builtin_amdgcn_s_setprio(1);
#pragma unroll
        for (int mi = 0; mi < 2; mi++)
#pragma unroll
            for (int pr = 0; pr < 2; pr++)
                lacc[mi] = __builtin_amdgcn_mfma_f32_16x16x32_bf16(pa_p[mi][pr], onesv, lacc[mi], 0, 0, 0);
#pragma unroll
        for (int mi = 0; mi < 2; mi++)
#pragma unroll
            for (int dt = 0; dt < 4; dt++)
#pragma unroll
                for (int pr = 0; pr < 2; pr++)
                    o[mi][dt] = __builtin_amdgcn_mfma_f32_16x16x32_bf16(pa_p[mi][pr], vc_p[dt * 2 + pr], o[mi][dt], 0, 0, 0);
        __builtin_amdgcn_s_setprio(0);

        // epilogue: store raw fp32 partials; l already in C-layout via ones-MFMA
#pragma unroll
        for (int mi = 0; mi < 2; mi++)
#pragma unroll
            for (int r = 0; r < 4; r++) {
                int row = qw + mi * 16 + quad * 4 + r;
#pragma unroll
                for (int dt = 0; dt < 4; dt++)
                    Of[row * DM + h * HD + dt * 16 + l15] = o[mi][dt][r];
            }
        if (l15 == 0) {
#pragma unroll
            for (int mi = 0; mi < 2; mi++)
#pragma unroll
                for (int r = 0; r < 4; r++)
                    Lf[h * SEQ + qw + mi * 16 + quad * 4 + r] = lacc[mi][r];
        }
    }
}

// ------------- combine split-s partials: ao = (sum O_j)/(sum l_j), cast bf16 -------------
// Coverage (from the 22-tile job schedule): q-tile t, b = min(t,31-t):
//   t <= 15 (low tile of pair):  buffer 0 always; buffer 1 iff b >= 11; never 2.
//   t >= 16 (high tile of pair): buffers 1,2 always; buffer 0 iff b <= 9.
__global__ void attn_finalize(const float* __restrict__ Of0, const float* __restrict__ Of1,
                              const float* __restrict__ Of2,
                              const float* __restrict__ Lf0, const float* __restrict__ Lf1,
                              const float* __restrict__ Lf2,
                              short* __restrict__ ao) {
    int i = blockIdx.x * blockDim.x + threadIdx.x;   // SEQ*DM/4 threads, float4 each
    int q  = i >> 8;           // / (DM/4)
    int c4 = i & 255;
    int h  = c4 >> 4;          // (c4*4) / 64
    int t  = q >> 7;
    bool lowq = (t < 16);
    int b = lowq ? t : 31 - t;
    bool use0 = lowq || (b <= 9);
    bool use1 = (!lowq) || (b >= 11);
    bool use2 = !lowq;

    float l = 0.f;
    float4v acc = {0.f, 0.f, 0.f, 0.f};
    if (use0) {
        l += Lf0[h * SEQ + q];
        float4v a = ((const float4v*)Of0)[i];
        acc[0] += a[0]; acc[1] += a[1]; acc[2] += a[2]; acc[3] += a[3];
    }
    if (use1) {
        l += Lf1[h * SEQ + q];
        float4v a = ((const float4v*)Of1)[i];
        acc[0] += a[0]; acc[1] += a[1]; acc[2] += a[2]; acc[3] += a[3];
    }
    if (use2) {
        l += Lf2[h * SEQ + q];
        float4v a = ((const float4v*)Of2)[i];
        acc[0] += a[0]; acc[1] += a[1]; acc[2] += a[2]; acc[3] += a[3];
    }
    float inv = 1.0f / l;
    short4v o;
    o[0] = f2bf(acc[0] * inv);
    o[1] = f2bf(acc[1] * inv);
    o[2] = f2bf(acc[2] * inv);
    o[3] = f2bf(acc[3] * inv);
    ((short4v*)ao)[i] = o;
}

extern "C" void kernel_launch(void* const* d_in, const int* in_sizes, int n_in,
                              void* d_out, int out_size, void* d_ws, size_t ws_size,
                              hipStream_t stream) {
    const float* x    = (const float*)d_in[0];
    const float* Wqkv = (const float*)d_in[1];
    const float* Wout = (const float*)d_in[2];
    float* out = (float*)d_out;

    char* ws = (char*)d_ws;
    // liveness-packed layout (peak ~78.4 MB):
    //   [0, 8M)          xb    bf16 4096x1024    (dead after gemm1)
    //   [8M, 14.68M)     wqkvT bf16 3072x1024    (dead after gemm1)
    //   [0, 16.78M)      Of0   fp32 4096x1024    (overlays xb+wqkvT; written in attn)
    //   d_out            Of1   fp32 4096x1024    (dead until gemm2 -> free scratch)
    //   [16.78M, 41.94M) qkv   bf16 4096x3072
    //   [41.94M, 50.33M) vt    bf16 16x64x4096
    //   [50.33M, 58.72M) ao    bf16 4096x1024    (written by finalize)
    //   [58.72M, 75.50M) Of2   fp32 4096x1024
    //   [75.50M, 75.76M) Lf0   fp32 16x4096
    //   [75.76M, 76.02M) Lf1   fp32 16x4096
    //   [76.02M, 76.28M) Lf2   fp32 16x4096
    //   [76.28M, 78.38M) woutT bf16 1024x1024
    short* xb    = (short*)(ws);
    short* wqkvT = (short*)(ws + 8388608);
    float* Of0   = (float*)(ws);
    float* Of1   = (float*)(d_out);
    short* qkv   = (short*)(ws + 16777216);
    short* vt    = (short*)(ws + 41943040);
    short* ao    = (short*)(ws + 50331648);
    float* Of2   = (float*)(ws + 58720256);
    float* Lf0   = (float*)(ws + 75497472);
    float* Lf1   = (float*)(ws + 75759616);
    float* Lf2   = (float*)(ws + 76021760);
    short* woutT = (short*)(ws + 76283904);

    prep<<<8192, 256, 0, stream>>>(x, Wqkv, Wout, xb, wqkvT, woutT);

    gemm_bt<short><<<dim3(3 * DM / 128, SEQ / 128), 256, 0, stream>>>(xb, wqkvT, qkv, SEQ, 3 * DM, DM);

    transpose_v<<<dim3(SEQ / 64, 1, NH), dim3(32, 8), 0, stream>>>(qkv, vt);

    attn_kernel<<<768, 256, 0, stream>>>(qkv, vt, Of0, Of1, Of2, Lf0, Lf1, Lf2);
    attn_finalize<<<(SEQ * DM / 4) / 256, 256, 0, stream>>>(Of0, Of1, Of2, Lf0, Lf1, Lf2, ao);

    gemm_bt64<<<dim3(DM / 128, SEQ / 64), 256, 0, stream>>>(ao, woutT, out, SEQ, DM, DM);
}

// Round 16
// 183.735 us; speedup vs baseline: 1.0332x; 1.0332x over previous
//
#include <hip/hip_runtime.h>

#define SEQ 4096
#define DM 1024
#define NH 16
#define HD 64

typedef __attribute__((ext_vector_type(8))) short short8;
typedef __attribute__((ext_vector_type(4))) short short4v;
typedef __attribute__((ext_vector_type(2))) short short2v;
typedef __attribute__((ext_vector_type(4))) float float4v;
typedef __attribute__((ext_vector_type(4))) int int4v;

__device__ __forceinline__ short f2bf(float f) {
    union { float f; unsigned u; } v; v.f = f;
    unsigned u = v.u;
    return (short)((u + 0x7fffu + ((u >> 16) & 1u)) >> 16);
}
// pack two fp32 -> dword of two bf16 via HW cvt_pk (1 VALU; no builtin on gfx950)
__device__ __forceinline__ int cvtpk(float lo, float hi) {
    int r;
    asm("v_cvt_pk_bf16_f32 %0, %1, %2" : "=v"(r) : "v"(lo), "v"(hi));
    return r;
}

__device__ __forceinline__ void gload_lds16(const void* g, void* l) {
    __builtin_amdgcn_global_load_lds(
        (const __attribute__((address_space(1))) void*)g,
        (__attribute__((address_space(3))) void*)l, 16, 0, 0);
}

// ---- fused prep: cast x (fp32->bf16) + transpose_cast Wqkv + transpose_cast Wout ----
// 3 launches -> 1. Flat 8192-block grid:
//   [0,4096): cast_x float4 blocks; [4096,7168): Wqkv 32x32 transpose tiles;
//   [7168,8192): Wout tiles. 256 threads flat; transpose remaps to (32,8).
__global__ __launch_bounds__(256) void prep(const float* __restrict__ x,
                                            const float* __restrict__ Wqkv,
                                            const float* __restrict__ Wout,
                                            short* __restrict__ xb,
                                            short* __restrict__ wqkvT,
                                            short* __restrict__ woutT) {
    __shared__ float tile[32][33];
    int bid = blockIdx.x;
    int tid = threadIdx.x;
    if (bid < 4096) {
        int i = bid * 256 + tid;               // SEQ*DM/4 float4 elems
        float4v v = ((const float4v*)x)[i];
        short4v o;
        o[0] = f2bf(v[0]); o[1] = f2bf(v[1]); o[2] = f2bf(v[2]); o[3] = f2bf(v[3]);
        ((short4v*)xb)[i] = o;
        return;
    }
    const float* in;
    short* out;
    int W, bxi, byi;
    float scale;
    int scaled_rows;
    if (bid < 4096 + 3072) {                   // Wqkv: [1024][3072] -> [3072][1024]
        int b = bid - 4096;
        in = Wqkv; out = wqkvT; W = 3 * DM;
        bxi = b % 96; byi = b / 96;
        scale = 0.18033688011112042f;          // (1/sqrt(64)) * log2(e)
        scaled_rows = DM;
    } else {                                   // Wout: [1024][1024] -> [1024][1024]
        int b = bid - 7168;
        in = Wout; out = woutT; W = DM;
        bxi = b % 32; byi = b / 32;
        scale = 1.0f;
        scaled_rows = 0;
    }
    int bx = bxi * 32, by = byi * 32;
    int tx = tid & 31, ty = tid >> 5;          // 32 x 8
#pragma unroll
    for (int i = 0; i < 32; i += 8)
        tile[ty + i][tx] = in[(by + ty + i) * W + bx + tx];
    __syncthreads();
#pragma unroll
    for (int i = 0; i < 32; i += 8) {
        int orow = bx + ty + i;
        float sc = (orow < scaled_rows) ? scale : 1.0f;
        out[orow * DM + by + tx] = f2bf(tile[tx][ty + i] * sc);
    }
}

// ------- V transpose: qkv bf16 [l][2048+h*64+d] -> vt [h][d][swz(l)] -------
// k-swizzle within each 32-col block so the attn PV B-fragment (k-permuted MFMA)
// reads plain short8 at quad*8: swz(s) = (s&~31)|((s&12)<<1)|((s&16)>>2)|(s&3).
__global__ void transpose_v(const short* __restrict__ qkv, short* __restrict__ vt) {
    __shared__ short tile[64][66];
    int h = blockIdx.z;
    int l0 = blockIdx.x * 64;
    int tx = threadIdx.x, ty = threadIdx.y;   // 32 x 8
#pragma unroll
    for (int i = 0; i < 8; i++) {
        int r = ty + i * 8;
        short2v v = *(const short2v*)&qkv[(l0 + r) * (3 * DM) + 2 * DM + h * HD + 2 * tx];
        tile[r][2 * tx] = v[0];
        tile[r][2 * tx + 1] = v[1];
    }
    __syncthreads();
#pragma unroll
    for (int i = 0; i < 8; i++) {
        int d = ty + i * 8;
        short2v v;
        v[0] = tile[2 * tx][d];
        v[1] = tile[2 * tx + 1][d];
        int s = l0 + 2 * tx;   // even -> swz keeps the pair contiguous
        int soff = (s & ~31) | ((s & 12) << 1) | ((s & 16) >> 2) | (s & 3);
        *(short2v*)&vt[(h * HD + d) * SEQ + soff] = v;
    }
}

// ------------- GEMM: A[M,K] bf16 x BT[N,K] bf16 -> C[M,N], 128x128 tile -------------
// R17-exact (session best): BK=64 + both-sides XOR swizzle, natural block order.
template <typename OutT>
__global__ __launch_bounds__(256) void gemm_bt(const short* __restrict__ A,
                                               const short* __restrict__ BT,
                                               OutT* __restrict__ C,
                                               int M, int N, int K) {
    __shared__ short As[128 * 64];   // 16 KB
    __shared__ short Bs[128 * 64];   // 16 KB
    int tid  = threadIdx.x;
    int m0   = blockIdx.y * 128;
    int n0   = blockIdx.x * 128;
    int w    = tid >> 6, lane = tid & 63;
    int wm   = w >> 1,  wn   = w & 1;
    int quad = lane >> 4, l15 = lane & 15;
    int lrow = lane >> 3;            // 0..7 row within 8-row DMA stripe
    int cg   = (lane & 7) ^ lrow;    // pre-swizzled source chunk
    int xr   = (l15 & 7) * 8;        // read-side XOR, in shorts

    float4v acc[4][4];
#pragma unroll
    for (int mi = 0; mi < 4; mi++)
#pragma unroll
        for (int ni = 0; ni < 4; ni++)
            acc[mi][ni] = {0.f, 0.f, 0.f, 0.f};

    for (int k0 = 0; k0 < K; k0 += 64) {
        __syncthreads();
#pragma unroll
        for (int t = 0; t < 4; t++) {
            int c = w * 4 + t;           // 16 chunks of 8 rows
            int r = c * 8 + lrow;
            gload_lds16(&A[(m0 + r) * K + k0 + cg * 8], &As[c * 8 * 64]);
            gload_lds16(&BT[(n0 + r) * K + k0 + cg * 8], &Bs[c * 8 * 64]);
        }
        __syncthreads();
        short8 a[4][2], b[4][2];
#pragma unroll
        for (int mi = 0; mi < 4; mi++)
#pragma unroll
            for (int kk = 0; kk < 2; kk++)
                a[mi][kk] = *(const short8*)&As[(wm * 64 + mi * 16 + l15) * 64 + (((kk * 4 + quad) * 8) ^ xr)];
#pragma unroll
        for (int ni = 0; ni < 4; ni++)
#pragma unroll
            for (int kk = 0; kk < 2; kk++)
                b[ni][kk] = *(const short8*)&Bs[(wn * 64 + ni * 16 + l15) * 64 + (((kk * 4 + quad) * 8) ^ xr)];
#pragma unroll
        for (int kk = 0; kk < 2; kk++)
#pragma unroll
            for (int mi = 0; mi < 4; mi++)
#pragma unroll
                for (int ni = 0; ni < 4; ni++)
                    acc[mi][ni] = __builtin_amdgcn_mfma_f32_16x16x32_bf16(a[mi][kk], b[ni][kk], acc[mi][ni], 0, 0, 0);
    }

#pragma unroll
    for (int mi = 0; mi < 4; mi++)
#pragma unroll
        for (int ni = 0; ni < 4; ni++)
#pragma unroll
            for (int r = 0; r < 4; r++) {
                int row = m0 + wm * 64 + mi * 16 + quad * 4 + r;
                int col = n0 + wn * 64 + ni * 16 + l15;
                float v = acc[mi][ni][r];
                if constexpr (sizeof(OutT) == 2) C[row * N + col] = (OutT)f2bf(v);
                else                             C[row * N + col] = (OutT)v;
            }
}

// ------------- GEMM 64x128 tile (small-N GEMM2; BK=64 + both-sides XOR swizzle) -------------
__global__ __launch_bounds__(256) void gemm_bt64(const short* __restrict__ A,
                                                 const short* __restrict__ BT,
                                                 float* __restrict__ C,
                                                 int M, int N, int K) {
    __shared__ short As[64 * 64];    // 8 KB
    __shared__ short Bs[128 * 64];   // 16 KB
    int tid  = threadIdx.x;
    int m0   = blockIdx.y * 64;
    int n0   = blockIdx.x * 128;
    int w    = tid >> 6, lane = tid & 63;
    int wm   = w >> 1,  wn   = w & 1;
    int quad = lane >> 4, l15 = lane & 15;
    int lrow = lane >> 3;
    int cg   = (lane & 7) ^ lrow;
    int xr   = (l15 & 7) * 8;

    float4v acc[2][4];
#pragma unroll
    for (int mi = 0; mi < 2; mi++)
#pragma unroll
        for (int ni = 0; ni < 4; ni++)
            acc[mi][ni] = {0.f, 0.f, 0.f, 0.f};

    for (int k0 = 0; k0 < K; k0 += 64) {
        __syncthreads();
#pragma unroll
        for (int t = 0; t < 2; t++) {
            int c = w * 2 + t;           // 8 chunks of 8 rows (A: 64 rows)
            int r = c * 8 + lrow;
            gload_lds16(&A[(m0 + r) * K + k0 + cg * 8], &As[c * 8 * 64]);
        }
#pragma unroll
        for (int t = 0; t < 4; t++) {
            int c = w * 4 + t;           // 16 chunks of 8 rows (B: 128 rows)
            int r = c * 8 + lrow;
            gload_lds16(&BT[(n0 + r) * K + k0 + cg * 8], &Bs[c * 8 * 64]);
        }
        __syncthreads();
        short8 a[2][2], b[4][2];
#pragma unroll
        for (int mi = 0; mi < 2; mi++)
#pragma unroll
            for (int kk = 0; kk < 2; kk++)
                a[mi][kk] = *(const short8*)&As[(wm * 32 + mi * 16 + l15) * 64 + (((kk * 4 + quad) * 8) ^ xr)];
#pragma unroll
        for (int ni = 0; ni < 4; ni++)
#pragma unroll
            for (int kk = 0; kk < 2; kk++)
                b[ni][kk] = *(const short8*)&Bs[(wn * 64 + ni * 16 + l15) * 64 + (((kk * 4 + quad) * 8) ^ xr)];
#pragma unroll
        for (int kk = 0; kk < 2; kk++)
#pragma unroll
            for (int mi = 0; mi < 2; mi++)
#pragma unroll
                for (int ni = 0; ni < 4; ni++)
                    acc[mi][ni] = __builtin_amdgcn_mfma_f32_16x16x32_bf16(a[mi][kk], b[ni][kk], acc[mi][ni], 0, 0, 0);
    }

#pragma unroll
    for (int mi = 0; mi < 2; mi++)
#pragma unroll
        for (int ni = 0; ni < 4; ni++)
#pragma unroll
            for (int r = 0; r < 4; r++) {
                int row = m0 + wm * 32 + mi * 16 + quad * 4 + r;
                int col = n0 + wn * 64 + ni * 16 + l15;
                C[row * N + col] = acc[mi][ni][r];
            }
}

// ------------- flash attention, causal, bf16 MFMA, DMA-staged K/V -------------
// R21-exact (session best: attn 50.5 us, total 186.7). Two 64-s tiles per barrier
// pair: 4 LDS slots (64 KB); phase = {stage tt+2,tt+3 -> proc(tt) -> proc(tt+1) ->
// lgkm(0)+vmcnt(0)+barrier}. Loop-carried pa_p/vc_p deferred-PV chain (PV of tile
// A fires during tile B's QK in-phase). R22's masked-tile skip REVERTED: the branch
// raised VGPR 100->116 and cost 2.7 us (control-flow divergence broke the
// compiler's straight-line schedule; same lesson class as R14).
__global__ __launch_bounds__(256, 2) void attn_kernel(const short* __restrict__ qkv,
                                                      const short* __restrict__ vtp,
                                                      float* __restrict__ Of0,
                                                      float* __restrict__ Of1,
                                                      float* __restrict__ Of2,
                                                      float* __restrict__ Lf0,
                                                      float* __restrict__ Lf1,
                                                      float* __restrict__ Lf2) {
    __shared__ short Ks[4][64 * 64];    // linear, DMA-written (8 KB each; 64 KB total K+V)
    __shared__ short Vs[4][64 * 64];
    int gid = blockIdx.x;            // 0..767
    int rr = gid & 7, qq = gid >> 3; // qq 0..95; gid%8 pins XCD = h%8 (2 heads/XCD)
    int hb = qq / 48;
    int rem = qq - hb * 48;          // 0..47
    int h = rr + 8 * hb;
    int b = rem & 15;                // pair index: q-tiles (b, 31-b)
    int j = rem >> 4;                // job 0..2 -> partial buffer j
    float* __restrict__ Of = (j == 0) ? Of0 : (j == 1) ? Of1 : Of2;
    float* __restrict__ Lf = (j == 0) ? Lf0 : (j == 1) ? Lf1 : Lf2;
    int B0 = 2 * b + 2;              // concat boundary between the pair's q-tiles

    int tid = threadIdx.x;
    int w = tid >> 6, lane = tid & 63;
    int quad = lane >> 4, l15 = lane & 15;
    int rowb = w * 16;               // wave's 16 staging rows
    int lrow = lane >> 3;            // 0..7: row within the 8-row DMA stripe
    int cg   = (lane & 7) ^ lrow;    // pre-swizzled source chunk (XOR both-sides)
    int xr   = (l15 & 7) * 8;        // read-side XOR, in shorts

    const short* Kg = qkv + DM + h * HD;     // + s*3072 + chunk*8
    const short* Vg = vtp + (h * HD) * SEQ;  // + d*4096 + s + chunk*8

    short8 onesv;                    // bf16 1.0 x8 (B-operand for l-accumulation MFMA)
#pragma unroll
    for (int i = 0; i < 8; i++) onesv[i] = (short)0x3F80;

#pragma unroll 1
    for (int sg = 0; sg < 2; sg++) {
        int t, st0, stN;
        if (sg == 0) {               // segment in q-tile b: concat tiles [22j,22j+22) ∩ [0,B0)
            t = b;
            st0 = 22 * j;
            stN = (22 * j + 22 < B0) ? 22 * j + 22 : B0;
        } else {                     // segment in q-tile 31-b: concat ∩ [B0,66), rebased
            t = 31 - b;
            int a0 = 22 * j - B0;
            st0 = (a0 > 0) ? a0 : 0;
            stN = 22 * j + 22 - B0;
        }
        if (st0 >= stN) continue;    // block-uniform

        int q0 = t * 128;
        int qw = q0 + w * 32;

        // Q fragments (B-operand of the S^T MFMA); Q pre-scaled by 0.125*log2e
        short8 aq[2][2];
#pragma unroll
        for (int mi = 0; mi < 2; mi++)
#pragma unroll
            for (int kk = 0; kk < 2; kk++)
                aq[mi][kk] = *(const short8*)&qkv[(qw + mi * 16 + l15) * (3 * DM) + h * HD + kk * 32 + quad * 8];

        float4v lacc[2];
        float4v o[2][4];
#pragma unroll
        for (int mi = 0; mi < 2; mi++) {
            lacc[mi] = {0.f, 0.f, 0.f, 0.f};
#pragma unroll
            for (int dt = 0; dt < 4; dt++)
                o[mi][dt] = {0.f, 0.f, 0.f, 0.f};
        }

        // DMA-stage one 64-s K/V tile into LDS slot (4 gload_lds per wave)
        auto stage = [&](int slot, int tt_) {
            int s0_ = tt_ * 64;
#pragma unroll
            for (int i = 0; i < 2; i++) {
                int r = rowb + i * 8;
                gload_lds16(&Kg[(s0_ + r + lrow) * (3 * DM) + cg * 8], &Ks[slot][r * 64]);
                gload_lds16(&Vg[(r + lrow) * SEQ + s0_ + cg * 8],      &Vs[slot][r * 64]);
            }
        };

        short8 pa_p[2][2];   // P(prev tile) bf16 fragments, loop-carried
        short8 vc_p[8];      // V(prev tile) fragments, loop-carried (refilled in place)

        // per-tile body: kc reads -> PV(prev) under read shadow -> vc_p refill ->
        // QK -> mask/exp -> pack into pa_p.  Identical math to R13.
        auto procTile = [&](int slot, int tt, bool doPV) {
            const short* Kb = &Ks[slot][0];
            const short* Vb = &Vs[slot][0];
            int s0 = tt * 64;

            short8 kc[8];
#pragma unroll
            for (int ni = 0; ni < 4; ni++)
#pragma unroll
                for (int kk = 0; kk < 2; kk++)
                    kc[ni * 2 + kk] = *(const short8*)&Kb[(ni * 16 + l15) * 64 + (((kk * 4 + quad) * 8) ^ xr)];

            if (doPV) {
                __builtin_amdgcn_s_setprio(1);
#pragma unroll
                for (int mi = 0; mi < 2; mi++)
#pragma unroll
                    for (int pr = 0; pr < 2; pr++)
                        lacc[mi] = __builtin_amdgcn_mfma_f32_16x16x32_bf16(pa_p[mi][pr], onesv, lacc[mi], 0, 0, 0);
#pragma unroll
                for (int mi = 0; mi < 2; mi++)
#pragma unroll
                    for (int dt = 0; dt < 4; dt++)
#pragma unroll
                        for (int pr = 0; pr < 2; pr++)
                            o[mi][dt] = __builtin_amdgcn_mfma_f32_16x16x32_bf16(pa_p[mi][pr], vc_p[dt * 2 + pr], o[mi][dt], 0, 0, 0);
                __builtin_amdgcn_s_setprio(0);
            }

#pragma unroll
            for (int dt = 0; dt < 4; dt++)
#pragma unroll
                for (int pr = 0; pr < 2; pr++)
                    vc_p[dt * 2 + pr] = *(const short8*)&Vb[(dt * 16 + l15) * 64 + (((pr * 4 + quad) * 8) ^ xr)];

            float4v s[2][4];
            __builtin_amdgcn_s_setprio(1);
#pragma unroll
            for (int mi = 0; mi < 2; mi++)
#pragma unroll
                for (int ni = 0; ni < 4; ni++) {
                    float4v a = {0.f, 0.f, 0.f, 0.f};
#pragma unroll
                    for (int kk = 0; kk < 2; kk++)
                        a = __builtin_amdgcn_mfma_f32_16x16x32_bf16(kc[ni * 2 + kk], aq[mi][kk], a, 0, 0, 0);
                    s[mi][ni] = a;
                }
            __builtin_amdgcn_s_setprio(0);

            bool diag = (s0 + 63 > qw);
            if (diag) {
#pragma unroll
                for (int mi = 0; mi < 2; mi++) {
                    int qrow = qw + mi * 16 + l15;
#pragma unroll
                    for (int ni = 0; ni < 4; ni++)
#pragma unroll
                        for (int r = 0; r < 4; r++) {
                            float p = __builtin_amdgcn_exp2f(s[mi][ni][r]);
                            int scol = s0 + ni * 16 + quad * 4 + r;
                            s[mi][ni][r] = (scol <= qrow) ? p : 0.f;
                        }
                }
            } else {
#pragma unroll
                for (int mi = 0; mi < 2; mi++)
#pragma unroll
                    for (int ni = 0; ni < 4; ni++)
#pragma unroll
                        for (int r = 0; r < 4; r++)
                            s[mi][ni][r] = __builtin_amdgcn_exp2f(s[mi][ni][r]);
            }
#pragma unroll
            for (int mi = 0; mi < 2; mi++)
#pragma unroll
                for (int pr = 0; pr < 2; pr++) {
                    int4v wpk;
                    wpk[0] = cvtpk(s[mi][2 * pr][0], s[mi][2 * pr][1]);
                    wpk[1] = cvtpk(s[mi][2 * pr][2], s[mi][2 * pr][3]);
                    wpk[2] = cvtpk(s[mi][2 * pr + 1][0], s[mi][2 * pr + 1][1]);
                    wpk[3] = cvtpk(s[mi][2 * pr + 1][2], s[mi][2 * pr + 1][3]);
                    pa_p[mi][pr] = *(short8*)&wpk;
                }
        };

        // prologue: stage first (up to) 2 tiles into slots 0,1
        stage(0, st0);
        if (st0 + 1 < stN) stage(1, st0 + 1);
        asm volatile("s_waitcnt vmcnt(0)" ::: "memory");
        __builtin_amdgcn_s_barrier();
        __builtin_amdgcn_sched_barrier(0);

        int L = stN - st0;
        int tt = st0, si = 0;
        bool first = true;

        if (L & 1) {                 // single-tile lead-in phase
            if (tt + 2 < stN) stage(2, tt + 2);
            procTile(0, tt, false);
            asm volatile("s_waitcnt lgkmcnt(0)" ::: "memory");
            asm volatile("s_waitcnt vmcnt(0)" ::: "memory");
            __builtin_amdgcn_s_barrier();
            __builtin_amdgcn_sched_barrier(0);
            tt += 1; si = 1; first = false;
        }

        for (; tt < stN; tt += 2) {  // two tiles per barrier pair
            int sA = si, sB = (si + 1) & 3, sC = (si + 2) & 3, sD = (si + 3) & 3;
            if (tt + 2 < stN) stage(sC, tt + 2);
            if (tt + 3 < stN) stage(sD, tt + 3);

            procTile(sA, tt, !first);
            procTile(sB, tt + 1, true);
            first = false;

            asm volatile("s_waitcnt lgkmcnt(0)" ::: "memory");
            asm volatile("s_waitcnt vmcnt(0)" ::: "memory");
            __builtin_amdgcn_s_barrier();
            __builtin_amdgcn_sched_barrier(0);
            si = sC;
        }

        // final deferred PV + l of tile stN-1 (carried in pa_p / vc_p)
        __builtin_amdgcn_s_setprio(1);
#pragma unroll
        for (int mi = 0; mi < 2; mi++)
#pragma unroll
            for (int pr = 0; pr < 2; pr++)
                lacc[mi] = __builtin_amdgcn_mfma_f32_16x16x32_bf16(pa_p[mi][pr], onesv, lacc[mi], 0, 0, 0);
#pragma unroll
        for (int mi = 0; mi < 2; mi++)
#pragma unroll
            for (int dt = 0; dt < 4; dt++)
#pragma unroll
                for (int pr = 0; pr < 2; pr++)
                    o[mi][dt] = __builtin_amdgcn_mfma_f32_16x16x32_bf16(pa_p[mi][pr], vc_p[dt * 2 + pr], o[mi][dt], 0, 0, 0);
        __builtin_amdgcn_s_setprio(0);

        // epilogue: store raw fp32 partials; l already in C-layout via ones-MFMA
#pragma unroll
        for (int mi = 0; mi < 2; mi++)
#pragma unroll
            for (int r = 0; r < 4; r++) {
                int row = qw + mi * 16 + quad * 4 + r;
#pragma unroll
                for (int dt = 0; dt < 4; dt++)
                    Of[row * DM + h * HD + dt * 16 + l15] = o[mi][dt][r];
            }
        if (l15 == 0) {
#pragma unroll
            for (int mi = 0; mi < 2; mi++)
#pragma unroll
                for (int r = 0; r < 4; r++)
                    Lf[h * SEQ + qw + mi * 16 + quad * 4 + r] = lacc[mi][r];
        }
    }
}

// ------------- combine split-s partials: ao = (sum O_j)/(sum l_j), cast bf16 -------------
// Coverage (from the 22-tile job schedule): q-tile t, b = min(t,31-t):
//   t <= 15 (low tile of pair):  buffer 0 always; buffer 1 iff b >= 11; never 2.
//   t >= 16 (high tile of pair): buffers 1,2 always; buffer 0 iff b <= 9.
__global__ void attn_finalize(const float* __restrict__ Of0, const float* __restrict__ Of1,
                              const float* __restrict__ Of2,
                              const float* __restrict__ Lf0, const float* __restrict__ Lf1,
                              const float* __restrict__ Lf2,
                              short* __restrict__ ao) {
    int i = blockIdx.x * blockDim.x + threadIdx.x;   // SEQ*DM/4 threads, float4 each
    int q  = i >> 8;           // / (DM/4)
    int c4 = i & 255;
    int h  = c4 >> 4;          // (c4*4) / 64
    int t  = q >> 7;
    bool lowq = (t < 16);
    int b = lowq ? t : 31 - t;
    bool use0 = lowq || (b <= 9);
    bool use1 = (!lowq) || (b >= 11);
    bool use2 = !lowq;

    float l = 0.f;
    float4v acc = {0.f, 0.f, 0.f, 0.f};
    if (use0) {
        l += Lf0[h * SEQ + q];
        float4v a = ((const float4v*)Of0)[i];
        acc[0] += a[0]; acc[1] += a[1]; acc[2] += a[2]; acc[3] += a[3];
    }
    if (use1) {
        l += Lf1[h * SEQ + q];
        float4v a = ((const float4v*)Of1)[i];
        acc[0] += a[0]; acc[1] += a[1]; acc[2] += a[2]; acc[3] += a[3];
    }
    if (use2) {
        l += Lf2[h * SEQ + q];
        float4v a = ((const float4v*)Of2)[i];
        acc[0] += a[0]; acc[1] += a[1]; acc[2] += a[2]; acc[3] += a[3];
    }
    float inv = 1.0f / l;
    short4v o;
    o[0] = f2bf(acc[0] * inv);
    o[1] = f2bf(acc[1] * inv);
    o[2] = f2bf(acc[2] * inv);
    o[3] = f2bf(acc[3] * inv);
    ((short4v*)ao)[i] = o;
}

extern "C" void kernel_launch(void* const* d_in, const int* in_sizes, int n_in,
                              void* d_out, int out_size, void* d_ws, size_t ws_size,
                              hipStream_t stream) {
    const float* x    = (const float*)d_in[0];
    const float* Wqkv = (const float*)d_in[1];
    const float* Wout = (const float*)d_in[2];
    float* out = (float*)d_out;

    char* ws = (char*)d_ws;
    // liveness-packed layout (peak ~78.4 MB):
    //   [0, 8M)          xb    bf16 4096x1024    (dead after gemm1)
    //   [8M, 14.68M)     wqkvT bf16 3072x1024    (dead after gemm1)
    //   [0, 16.78M)      Of0   fp32 4096x1024    (overlays xb+wqkvT; written in attn)
    //   d_out            Of1   fp32 4096x1024    (dead until gemm2 -> free scratch)
    //   [16.78M, 41.94M) qkv   bf16 4096x3072
    //   [41.94M, 50.33M) vt    bf16 16x64x4096
    //   [50.33M, 58.72M) ao    bf16 4096x1024    (written by finalize)
    //   [58.72M, 75.50M) Of2   fp32 4096x1024
    //   [75.50M, 75.76M) Lf0   fp32 16x4096
    //   [75.76M, 76.02M) Lf1   fp32 16x4096
    //   [76.02M, 76.28M) Lf2   fp32 16x4096
    //   [76.28M, 78.38M) woutT bf16 1024x1024
    short* xb    = (short*)(ws);
    short* wqkvT = (short*)(ws + 8388608);
    float* Of0   = (float*)(ws);
    float* Of1   = (float*)(d_out);
    short* qkv   = (short*)(ws + 16777216);
    short* vt    = (short*)(ws + 41943040);
    short* ao    = (short*)(ws + 50331648);
    float* Of2   = (float*)(ws + 58720256);
    float* Lf0   = (float*)(ws + 75497472);
    float* Lf1   = (float*)(ws + 75759616);
    float* Lf2   = (float*)(ws + 76021760);
    short* woutT = (short*)(ws + 76283904);

    prep<<<8192, 256, 0, stream>>>(x, Wqkv, Wout, xb, wqkvT, woutT);

    gemm_bt<short><<<dim3(3 * DM / 128, SEQ / 128), 256, 0, stream>>>(xb, wqkvT, qkv, SEQ, 3 * DM, DM);

    transpose_v<<<dim3(SEQ / 64, 1, NH), dim3(32, 8), 0, stream>>>(qkv, vt);

    attn_kernel<<<768, 256, 0, stream>>>(qkv, vt, Of0, Of1, Of2, Lf0, Lf1, Lf2);
    attn_finalize<<<(SEQ * DM / 4) / 256, 256, 0, stream>>>(Of0, Of1, Of2, Lf0, Lf1, Lf2, ao);

    gemm_bt64<<<dim3(DM / 128, SEQ / 64), 256, 0, stream>>>(ao, woutT, out, SEQ, DM, DM);
}